// Round 14
// baseline (227.176 us; speedup 1.0000x reference)
//
#include <hip/hip_runtime.h>
#include <math.h>

#define NTOK 87040
#define DIM 512
#define NH 8
#define C2 0.1803368801111204f   // log2(e) / sqrt(64)

typedef __attribute__((ext_vector_type(8))) short short8v;
typedef __attribute__((ext_vector_type(4))) float f32x4;

__device__ __forceinline__ unsigned packpair(float x, float y) {
    // bf16(x) | bf16(y)<<16  (truncating)
    return __builtin_amdgcn_perm(__float_as_uint(y), __float_as_uint(x), 0x07060302u);
}
__device__ __forceinline__ float bftrunc(float x) {
    return __uint_as_float(__float_as_uint(x) & 0xFFFF0000u);
}

// ---------------------------------------------------------------------------
// 8x64-tiled GEMM + bias: out = A @ W + b.  A:[1024x512] W:[512x512]
// grid(128, 8), 256 thr -> 1024 blocks (4 per CU, 4 waves/SIMD).
// Per-output k-order identical to rd13 -> bitwise-same results.
// ---------------------------------------------------------------------------
__global__ __launch_bounds__(256)
void k_gemm2(const float* __restrict__ A, const float* __restrict__ W,
             const float* __restrict__ bias, float* __restrict__ out) {
    __shared__ float As[32][9];    // [k][row], stride 9 (gcd(9,32)=1: conflict-free)
    __shared__ float Bs[32][68];   // [k][col]
    const int rb = blockIdx.x, cb = blockIdx.y, t = threadIdx.x;
    const int row = t >> 5, cl = t & 31;   // output: 1 row x 2 cols per thread
    float acc[2] = {0.f, 0.f};

    for (int kb = 0; kb < 16; ++kb) {
        {
            // As: thread t loads A[rb*8 + (t>>5)][kb*32 + (t&31)]
            As[cl][row] = A[(size_t)(rb * 8 + row) * 512 + kb * 32 + cl];
            const int kr = t >> 3, cq = t & 7;
            const float* bp = W + (size_t)(kb * 32 + kr) * 512 + cb * 64 + cq * 8;
            *(float4*)&Bs[kr][cq * 8]     = ((const float4*)bp)[0];
            *(float4*)&Bs[kr][cq * 8 + 4] = ((const float4*)bp)[1];
        }
        __syncthreads();
        #pragma unroll 8
        for (int k = 0; k < 32; ++k) {
            const float av = As[k][row];
            const float2 bw = *(const float2*)&Bs[k][cl * 2];
            acc[0] = fmaf(av, bw.x, acc[0]);
            acc[1] = fmaf(av, bw.y, acc[1]);
        }
        __syncthreads();
    }
    const int r = rb * 8 + row;
    const int c = cb * 64 + cl * 2;
    float2 o;
    o.x = acc[0] + bias[c];
    o.y = acc[1] + bias[c + 1];
    *(float2*)&out[(size_t)r * 512 + c] = o;
}

// ---------------------------------------------------------------------------
// k_qtilde: 8 per-head GEMMs: qt2[r, h*512+d] = C2 * sum_j Q[r,h*64+j]*Wk[d,h*64+j]
// grid(16 rb, 8 db, 8 h), 64x64 tile, K=64.  qb fused (db==0 blocks).
// [byte-identical to rd13]
// ---------------------------------------------------------------------------
__global__ __launch_bounds__(256)
void k_qtilde(const float* __restrict__ Q, const float* __restrict__ Wk,
              const float* __restrict__ bk, float* __restrict__ qt2,
              float* __restrict__ qb2) {
    __shared__ float AsT[64][68];
    __shared__ float Bs[64][68];
    const int rb = blockIdx.x, db = blockIdx.y, h = blockIdx.z, t = threadIdx.x;
    {
        const int row = t >> 2, j0 = (t & 3) * 16;
        const float* ap = Q + (size_t)(rb * 64 + row) * 512 + h * 64 + j0;
        #pragma unroll
        for (int a = 0; a < 4; ++a) {
            float4 v = ((const float4*)ap)[a];
            AsT[j0 + a * 4 + 0][row] = v.x; AsT[j0 + a * 4 + 1][row] = v.y;
            AsT[j0 + a * 4 + 2][row] = v.z; AsT[j0 + a * 4 + 3][row] = v.w;
        }
        const int d = t >> 2;
        const float* bp = Wk + (size_t)(db * 64 + d) * 512 + h * 64 + j0;
        #pragma unroll
        for (int a = 0; a < 4; ++a) {
            float4 v = ((const float4*)bp)[a];
            Bs[j0 + a * 4 + 0][d] = v.x; Bs[j0 + a * 4 + 1][d] = v.y;
            Bs[j0 + a * 4 + 2][d] = v.z; Bs[j0 + a * 4 + 3][d] = v.w;
        }
    }
    __syncthreads();
    if (db == 0 && t < 64) {
        float a = 0.f;
        #pragma unroll 8
        for (int j = 0; j < 64; ++j) a = fmaf(AsT[j][t], bk[h * 64 + j], a);
        qb2[(rb * 64 + t) * NH + h] = a * C2;
    }
    const int tx = t & 15, ty = t >> 4;
    float acc[4][4];
    #pragma unroll
    for (int i = 0; i < 4; ++i)
        #pragma unroll
        for (int j = 0; j < 4; ++j) acc[i][j] = 0.f;
    #pragma unroll 8
    for (int k = 0; k < 64; ++k) {
        float4 av = *(const float4*)&AsT[k][ty * 4];
        float4 bw = *(const float4*)&Bs[k][tx * 4];
        acc[0][0] = fmaf(av.x, bw.x, acc[0][0]); acc[0][1] = fmaf(av.x, bw.y, acc[0][1]);
        acc[0][2] = fmaf(av.x, bw.z, acc[0][2]); acc[0][3] = fmaf(av.x, bw.w, acc[0][3]);
        acc[1][0] = fmaf(av.y, bw.x, acc[1][0]); acc[1][1] = fmaf(av.y, bw.y, acc[1][1]);
        acc[1][2] = fmaf(av.y, bw.z, acc[1][2]); acc[1][3] = fmaf(av.y, bw.w, acc[1][3]);
        acc[2][0] = fmaf(av.z, bw.x, acc[2][0]); acc[2][1] = fmaf(av.z, bw.y, acc[2][1]);
        acc[2][2] = fmaf(av.z, bw.z, acc[2][2]); acc[2][3] = fmaf(av.z, bw.w, acc[2][3]);
        acc[3][0] = fmaf(av.w, bw.x, acc[3][0]); acc[3][1] = fmaf(av.w, bw.y, acc[3][1]);
        acc[3][2] = fmaf(av.w, bw.z, acc[3][2]); acc[3][3] = fmaf(av.w, bw.w, acc[3][3]);
    }
    #pragma unroll
    for (int i = 0; i < 4; ++i) {
        const int r = rb * 64 + ty * 4 + i;
        #pragma unroll
        for (int j = 0; j < 4; ++j)
            qt2[(size_t)r * 4096 + h * 512 + db * 64 + tx * 4 + j] = acc[i][j] * C2;
    }
}

// ---------------------------------------------------------------------------
// Kernel 3: MFMA window attention v2 (rd9 best-measured, byte-identical).
// ---------------------------------------------------------------------------
#define TSTRIDE 1040
#define KEYP  0       // 32*1040      = 33280
#define DIMP  33280   // 512*64       = 32768 -> 66048
#define PARTB 66048   // 4*32*16*4    =  8192 -> 74240
#define PLDSB 74240   // 16*64        =  1024 -> 75264
#define LDSZ  76800   // padded: 2 blocks/CU exactly

__device__ __forceinline__ int tok_addr(int key, int dimbyte) {
    return KEYP + key * TSTRIDE + (dimbyte ^ ((key & 7) << 4));
}

__global__ __launch_bounds__(256, 2)
void k_attn(const float* __restrict__ value, const float* __restrict__ tc_,
            const float* __restrict__ fc_, const float* __restrict__ qt2,
            const float* __restrict__ qb2, float* __restrict__ ts,
            float* __restrict__ lout) {
    __shared__ char smem[LDSZ];
    const int r = blockIdx.x, b = r >> 9, t = threadIdx.x;
    const int w = t >> 6, lane = t & 63;
    const int m = lane & 15, q = lane >> 4;
    const int dl = lane;

    const float tcf = tc_[r], fcf = fc_[r];
    const float* vb = value + (size_t)b * NTOK * DIM;

    *(float*)(smem + PLDSB + t * 4) = 0.f;

    short8v afr[4];
    #pragma unroll
    for (int ks = 0; ks < 4; ++ks) {
        const float* qp = qt2 + (size_t)r * 4096 + (lane & 7) * 512 + w * 128 + ks * 32 + q * 8;
        float4 x = ((const float4*)qp)[0], y = ((const float4*)qp)[1];
        union { unsigned u[4]; short8v s; } H, L;
        H.u[0] = packpair(x.x, x.y); H.u[1] = packpair(x.z, x.w);
        H.u[2] = packpair(y.x, y.y); H.u[3] = packpair(y.z, y.w);
        L.u[0] = packpair(x.x - bftrunc(x.x), x.y - bftrunc(x.y));
        L.u[1] = packpair(x.z - bftrunc(x.z), x.w - bftrunc(x.w));
        L.u[2] = packpair(y.x - bftrunc(y.x), y.y - bftrunc(y.y));
        L.u[3] = packpair(y.z - bftrunc(y.z), y.w - bftrunc(y.w));
        afr[ks] = (lane & 8) ? L.s : H.s;
    }
    const float qbh = qb2[r * NH + (t & 7)];
    const float eqb = __builtin_amdgcn_exp2f(qbh);

    const int kk = t >> 3, dh = t & 7;

    float4 va[16];
    auto issue_loads = [&](int kt) {
        const int lev = kt >> 2;
        const int Wl = 1024 >> lev, Hl = 64 >> lev;
        const int lsi = (lev == 0) ? 0 : (lev == 1) ? 65536 : (lev == 2) ? 81920 : 86016;
        const int tcpx = (int)rintf(tcf * (float)Wl - 0.5f);
        const int fcpx = (int)rintf(fcf * (float)Hl - 0.5f);
        #pragma unroll
        for (int i = 0; i < 8; ++i) {
            const int kl = (kt & 3) * 32 + w * 8 + i;
            const int tt = tcpx + (kl & 15) - 8;
            const int ff = fcpx + (kl >> 4) - 4;
            const int row = lsi + min(max(ff, 0), Hl - 1) * Wl + min(max(tt, 0), Wl - 1);
            const float* sp = vb + (size_t)row * DIM + dl * 8;
            va[2 * i]     = *(const float4*)sp;
            va[2 * i + 1] = *(const float4*)(sp + 4);
        }
    };
    issue_loads(0);

    f32x4 acco[8];
    #pragma unroll
    for (int nt = 0; nt < 8; ++nt) acco[nt] = (f32x4){0.f, 0.f, 0.f, 0.f};
    float lsum = 0.f;

    #pragma unroll
    for (int kt = 0; kt < 16; ++kt) {
        #pragma unroll
        for (int i = 0; i < 8; ++i) {
            float4 v0 = va[2 * i], v1 = va[2 * i + 1];
            uint4 H;
            H.x = packpair(v0.x, v0.y); H.y = packpair(v0.z, v0.w);
            H.z = packpair(v1.x, v1.y); H.w = packpair(v1.z, v1.w);
            const int key = w * 8 + i;
            *(uint4*)(smem + tok_addr(key, dl * 16)) = H;
        }
        #pragma unroll
        for (int dd = 0; dd < 8; ++dd) {
            uint4 D;
            const int hi = dd >> 2, c = dd & 3;
            D.x = packpair(((const float*)&va[0 + hi])[c],  ((const float*)&va[2 + hi])[c]);
            D.y = packpair(((const float*)&va[4 + hi])[c],  ((const float*)&va[6 + hi])[c]);
            D.z = packpair(((const float*)&va[8 + hi])[c],  ((const float*)&va[10 + hi])[c]);
            D.w = packpair(((const float*)&va[12 + hi])[c], ((const float*)&va[14 + hi])[c]);
            const int d = dl * 8 + dd;
            *(uint4*)(smem + DIMP + d * 64 + ((w * 16) ^ ((dl & 3) << 4))) = D;
        }
        if (kt < 15) issue_loads(kt + 1);
        __syncthreads();

        f32x4 dacc[2];
        dacc[0] = (f32x4){0.f, 0.f, 0.f, 0.f};
        dacc[1] = (f32x4){0.f, 0.f, 0.f, 0.f};
        #pragma unroll
        for (int ks = 0; ks < 4; ++ks) {
            const int dby = w * 256 + ks * 64 + q * 16;
            #pragma unroll
            for (int ko = 0; ko < 2; ++ko) {
                const int key = m + 16 * ko;
                short8v bhi = *(const short8v*)(smem + tok_addr(key, dby));
                dacc[ko] = __builtin_amdgcn_mfma_f32_16x16x32_bf16(afr[ks], bhi, dacc[ko], 0, 0, 0);
            }
        }
        *(f32x4*)(smem + PARTB + w * 2048 + m * 64 + q * 16)        = dacc[0];
        *(f32x4*)(smem + PARTB + w * 2048 + (m + 16) * 64 + q * 16) = dacc[1];
        __syncthreads();

        {
            float s = 0.f;
            #pragma unroll
            for (int w4 = 0; w4 < 4; ++w4) {
                s += *(const float*)(smem + PARTB + w4 * 2048 + kk * 64 + dh * 4);
                s += *(const float*)(smem + PARTB + w4 * 2048 + kk * 64 + (dh + 8) * 4);
            }
            const int lev = kt >> 2;
            const int Wl = 1024 >> lev, Hl = 64 >> lev;
            const int tcpx = (int)rintf(tcf * (float)Wl - 0.5f);
            const int fcpx = (int)rintf(fcf * (float)Hl - 0.5f);
            const int kl = (kt & 3) * 32 + kk;
            const int tt = tcpx + (kl & 15) - 8;
            const int ff = fcpx + (kl >> 4) - 4;
            const bool oob = (tt < 0) | (tt >= Wl) | (ff < 0) | (ff >= Hl);
            const float p = __builtin_amdgcn_exp2f(s + qbh);
            lsum += oob ? eqb : p;
            unsigned short pb = 0;
            if (!oob) {
                const unsigned u = __float_as_uint(p);
                pb = (unsigned short)((u + 0x7FFFu + ((u >> 16) & 1u)) >> 16);
            }
            *(unsigned short*)(smem + PLDSB + dh * 64 + kk * 2) = pb;
        }
        __syncthreads();

        {
            short8v pa = *(const short8v*)(smem + PLDSB + m * 64 + q * 16);
            #pragma unroll
            for (int nt = 0; nt < 8; ++nt) {
                const int d = w * 128 + nt * 16 + m;
                short8v bv = *(const short8v*)(smem + DIMP + d * 64 +
                                               ((q * 16) ^ (((d >> 3) & 3) << 4)));
                acco[nt] = __builtin_amdgcn_mfma_f32_16x16x32_bf16(pa, bv, acco[nt], 0, 0, 0);
            }
        }
        __syncthreads();
    }

    if (q < 2) {
        float* tsr = ts + (size_t)r * 4096 + (q * 4) * 512 + w * 128 + m;
        #pragma unroll
        for (int nt = 0; nt < 8; ++nt)
            #pragma unroll
            for (int jj = 0; jj < 4; ++jj)
                tsr[jj * 512 + nt * 16] = acco[nt][jj];
    }
    lsum += __shfl_xor(lsum, 8);
    lsum += __shfl_xor(lsum, 16);
    lsum += __shfl_xor(lsum, 32);
    if (lane < 8) *(float*)(smem + PARTB + (w * 8 + lane) * 4) = lsum;
    __syncthreads();
    if (t < 8) {
        float a = 0.f;
        #pragma unroll
        for (int w4 = 0; w4 < 4; ++w4)
            a += *(const float*)(smem + PARTB + (w4 * 8 + t) * 4);
        lout[r * NH + t] = a;
    }
}

// ---------------------------------------------------------------------------
// Kernel 4a: o1 = (ts/l) @ Wv + bv, 8x64 tiles, grid(128, 8) = 1024 blocks.
// ---------------------------------------------------------------------------
__global__ __launch_bounds__(256)
void k_gemm1(const float* __restrict__ ts, const float* __restrict__ lp,
             const float* __restrict__ Wv, const float* __restrict__ bv,
             float* __restrict__ o1) {
    __shared__ float As[32][9];
    __shared__ float Bs[32][68];
    const int rb = blockIdx.x, h = blockIdx.y, t = threadIdx.x;
    const int row = t >> 5, cl = t & 31;
    float acc[2] = {0.f, 0.f};

    for (int kb = 0; kb < 16; ++kb) {
        {
            As[cl][row] = ts[(size_t)(rb * 8 + row) * 4096 + h * 512 + kb * 32 + cl];
            const int kr = t >> 3, cq = t & 7;
            const float* bp = Wv + (size_t)(kb * 32 + kr) * 512 + h * 64 + cq * 8;
            *(float4*)&Bs[kr][cq * 8]     = ((const float4*)bp)[0];
            *(float4*)&Bs[kr][cq * 8 + 4] = ((const float4*)bp)[1];
        }
        __syncthreads();
        #pragma unroll 8
        for (int k = 0; k < 32; ++k) {
            const float av = As[k][row];
            const float2 bw = *(const float2*)&Bs[k][cl * 2];
            acc[0] = fmaf(av, bw.x, acc[0]);
            acc[1] = fmaf(av, bw.y, acc[1]);
        }
        __syncthreads();
    }
    const int r = rb * 8 + row;
    const float inv = 1.f / lp[r * NH + h];
    const int c = h * 64 + cl * 2;
    float2 o;
    o.x = acc[0] * inv + bv[c];
    o.y = acc[1] * inv + bv[c + 1];
    *(float2*)&o1[(size_t)r * 512 + c] = o;
}

// ---------------------------------------------------------------------------
extern "C" void kernel_launch(void* const* d_in, const int* in_sizes, int n_in,
                              void* d_out, int out_size, void* d_ws, size_t ws_size,
                              hipStream_t stream) {
    const float* query = (const float*)d_in[0];
    const float* tc    = (const float*)d_in[1];
    const float* fc    = (const float*)d_in[2];
    const float* value = (const float*)d_in[3];
    const float* Wq    = (const float*)d_in[4];
    const float* bq    = (const float*)d_in[5];
    const float* Wk    = (const float*)d_in[6];
    const float* bk    = (const float*)d_in[7];
    const float* Wv    = (const float*)d_in[8];
    const float* bv    = (const float*)d_in[9];
    const float* Wo    = (const float*)d_in[10];
    const float* bo    = (const float*)d_in[11];
    float* out = (float*)d_out;

    char* ws = (char*)d_ws;
    float* Q   = (float*)(ws);                      //  2 MB
    float* QT2 = (float*)(ws + (size_t)(2  << 20)); // 16 MB
    float* QB2 = (float*)(ws + (size_t)(18 << 20)); // 32 KB
    float* TS  = (float*)(ws + (size_t)(19 << 20)); // 16 MB
    float* L   = (float*)(ws + (size_t)(35 << 20)); // 32 KB
    float* O1  = (float*)(ws + (size_t)(36 << 20)); //  2 MB

    hipLaunchKernelGGL(k_gemm2,  dim3(128, 8),   dim3(256), 0, stream, query, Wq, bq, Q);
    hipLaunchKernelGGL(k_qtilde, dim3(16, 8, 8), dim3(256), 0, stream, Q, Wk, bk, QT2, QB2);
    hipLaunchKernelGGL(k_attn,   dim3(1024),     dim3(256), 0, stream,
                       value, tc, fc, QT2, QB2, TS, L);
    hipLaunchKernelGGL(k_gemm1,  dim3(128, 8),   dim3(256), 0, stream, TS, L, Wv, bv, O1);
    hipLaunchKernelGGL(k_gemm2,  dim3(128, 8),   dim3(256), 0, stream, O1, Wo, bo, out);
}

// Round 15
// 196.820 us; speedup vs baseline: 1.1542x; 1.1542x over previous
//
#include <hip/hip_runtime.h>
#include <math.h>

#define NTOK 87040
#define DIM 512
#define NH 8
#define C2 0.1803368801111204f   // log2(e) / sqrt(64)

typedef __attribute__((ext_vector_type(8))) short short8v;
typedef __attribute__((ext_vector_type(4))) float f32x4;

__device__ __forceinline__ unsigned packpair(float x, float y) {
    // bf16(x) | bf16(y)<<16  (truncating)
    return __builtin_amdgcn_perm(__float_as_uint(y), __float_as_uint(x), 0x07060302u);
}
__device__ __forceinline__ float bftrunc(float x) {
    return __uint_as_float(__float_as_uint(x) & 0xFFFF0000u);
}

// ---------------------------------------------------------------------------
// 16x64-tiled GEMM + bias: out = A @ W + b.  A:[1024x512] W:[512x512]
// grid(64, 8), 256 thr -> 512 blocks (2 per CU, 2 waves/SIMD).
// Measured optimum of the tile/occupancy curve: 128 > 256 > 512* < 1024 blocks.
// ---------------------------------------------------------------------------
__global__ __launch_bounds__(256)
void k_gemm2(const float* __restrict__ A, const float* __restrict__ W,
             const float* __restrict__ bias, float* __restrict__ out) {
    __shared__ float As[32][17];   // [k][row], pad 17: stores <=2-way (free)
    __shared__ float Bs[32][68];   // [k][col]
    const int rb = blockIdx.x, cb = blockIdx.y, t = threadIdx.x;
    const int tx = t & 15, ty = t >> 4;
    float acc[4] = {0.f, 0.f, 0.f, 0.f};

    for (int kb = 0; kb < 16; ++kb) {
        {
            const int row = t >> 4, kq = t & 15;   // 2 k-values per thread
            const float2 a0 = *(const float2*)(A + (size_t)(rb * 16 + row) * 512 + kb * 32 + kq * 2);
            As[kq * 2 + 0][row] = a0.x; As[kq * 2 + 1][row] = a0.y;
            const int kr = t >> 3, cq = t & 7;
            const float* bp = W + (size_t)(kb * 32 + kr) * 512 + cb * 64 + cq * 8;
            *(float4*)&Bs[kr][cq * 8]     = ((const float4*)bp)[0];
            *(float4*)&Bs[kr][cq * 8 + 4] = ((const float4*)bp)[1];
        }
        __syncthreads();
        #pragma unroll 8
        for (int k = 0; k < 32; ++k) {
            const float av = As[k][ty];
            float4 bw = *(const float4*)&Bs[k][tx * 4];
            acc[0] = fmaf(av, bw.x, acc[0]); acc[1] = fmaf(av, bw.y, acc[1]);
            acc[2] = fmaf(av, bw.z, acc[2]); acc[3] = fmaf(av, bw.w, acc[3]);
        }
        __syncthreads();
    }
    const int r = rb * 16 + ty;
    #pragma unroll
    for (int j = 0; j < 4; ++j) {
        const int c = cb * 64 + tx * 4 + j;
        out[(size_t)r * 512 + c] = acc[j] + bias[c];
    }
}

// ---------------------------------------------------------------------------
// k_qtilde: 8 per-head GEMMs: qt2[r, h*512+d] = C2 * sum_j Q[r,h*64+j]*Wk[d,h*64+j]
// grid(16 rb, 8 db, 8 h), 64x64 tile, K=64.  qb fused (db==0 blocks).
// ---------------------------------------------------------------------------
__global__ __launch_bounds__(256)
void k_qtilde(const float* __restrict__ Q, const float* __restrict__ Wk,
              const float* __restrict__ bk, float* __restrict__ qt2,
              float* __restrict__ qb2) {
    __shared__ float AsT[64][68];
    __shared__ float Bs[64][68];
    const int rb = blockIdx.x, db = blockIdx.y, h = blockIdx.z, t = threadIdx.x;
    {
        const int row = t >> 2, j0 = (t & 3) * 16;
        const float* ap = Q + (size_t)(rb * 64 + row) * 512 + h * 64 + j0;
        #pragma unroll
        for (int a = 0; a < 4; ++a) {
            float4 v = ((const float4*)ap)[a];
            AsT[j0 + a * 4 + 0][row] = v.x; AsT[j0 + a * 4 + 1][row] = v.y;
            AsT[j0 + a * 4 + 2][row] = v.z; AsT[j0 + a * 4 + 3][row] = v.w;
        }
        const int d = t >> 2;
        const float* bp = Wk + (size_t)(db * 64 + d) * 512 + h * 64 + j0;
        #pragma unroll
        for (int a = 0; a < 4; ++a) {
            float4 v = ((const float4*)bp)[a];
            Bs[j0 + a * 4 + 0][d] = v.x; Bs[j0 + a * 4 + 1][d] = v.y;
            Bs[j0 + a * 4 + 2][d] = v.z; Bs[j0 + a * 4 + 3][d] = v.w;
        }
    }
    __syncthreads();
    if (db == 0 && t < 64) {
        float a = 0.f;
        #pragma unroll 8
        for (int j = 0; j < 64; ++j) a = fmaf(AsT[j][t], bk[h * 64 + j], a);
        qb2[(rb * 64 + t) * NH + h] = a * C2;
    }
    const int tx = t & 15, ty = t >> 4;
    float acc[4][4];
    #pragma unroll
    for (int i = 0; i < 4; ++i)
        #pragma unroll
        for (int j = 0; j < 4; ++j) acc[i][j] = 0.f;
    #pragma unroll 8
    for (int k = 0; k < 64; ++k) {
        float4 av = *(const float4*)&AsT[k][ty * 4];
        float4 bw = *(const float4*)&Bs[k][tx * 4];
        acc[0][0] = fmaf(av.x, bw.x, acc[0][0]); acc[0][1] = fmaf(av.x, bw.y, acc[0][1]);
        acc[0][2] = fmaf(av.x, bw.z, acc[0][2]); acc[0][3] = fmaf(av.x, bw.w, acc[0][3]);
        acc[1][0] = fmaf(av.y, bw.x, acc[1][0]); acc[1][1] = fmaf(av.y, bw.y, acc[1][1]);
        acc[1][2] = fmaf(av.y, bw.z, acc[1][2]); acc[1][3] = fmaf(av.y, bw.w, acc[1][3]);
        acc[2][0] = fmaf(av.z, bw.x, acc[2][0]); acc[2][1] = fmaf(av.z, bw.y, acc[2][1]);
        acc[2][2] = fmaf(av.z, bw.z, acc[2][2]); acc[2][3] = fmaf(av.z, bw.w, acc[2][3]);
        acc[3][0] = fmaf(av.w, bw.x, acc[3][0]); acc[3][1] = fmaf(av.w, bw.y, acc[3][1]);
        acc[3][2] = fmaf(av.w, bw.z, acc[3][2]); acc[3][3] = fmaf(av.w, bw.w, acc[3][3]);
    }
    #pragma unroll
    for (int i = 0; i < 4; ++i) {
        const int r = rb * 64 + ty * 4 + i;
        #pragma unroll
        for (int j = 0; j < 4; ++j)
            qt2[(size_t)r * 4096 + h * 512 + db * 64 + tx * 4 + j] = acc[i][j] * C2;
    }
}

// ---------------------------------------------------------------------------
// Kernel 3: MFMA window attention v2 (rd9 best-measured, byte-identical).
// ---------------------------------------------------------------------------
#define TSTRIDE 1040
#define KEYP  0       // 32*1040      = 33280
#define DIMP  33280   // 512*64       = 32768 -> 66048
#define PARTB 66048   // 4*32*16*4    =  8192 -> 74240
#define PLDSB 74240   // 16*64        =  1024 -> 75264
#define LDSZ  76800   // padded: 2 blocks/CU exactly

__device__ __forceinline__ int tok_addr(int key, int dimbyte) {
    return KEYP + key * TSTRIDE + (dimbyte ^ ((key & 7) << 4));
}

__global__ __launch_bounds__(256, 2)
void k_attn(const float* __restrict__ value, const float* __restrict__ tc_,
            const float* __restrict__ fc_, const float* __restrict__ qt2,
            const float* __restrict__ qb2, float* __restrict__ ts,
            float* __restrict__ lout) {
    __shared__ char smem[LDSZ];
    const int r = blockIdx.x, b = r >> 9, t = threadIdx.x;
    const int w = t >> 6, lane = t & 63;
    const int m = lane & 15, q = lane >> 4;
    const int dl = lane;

    const float tcf = tc_[r], fcf = fc_[r];
    const float* vb = value + (size_t)b * NTOK * DIM;

    *(float*)(smem + PLDSB + t * 4) = 0.f;

    short8v afr[4];
    #pragma unroll
    for (int ks = 0; ks < 4; ++ks) {
        const float* qp = qt2 + (size_t)r * 4096 + (lane & 7) * 512 + w * 128 + ks * 32 + q * 8;
        float4 x = ((const float4*)qp)[0], y = ((const float4*)qp)[1];
        union { unsigned u[4]; short8v s; } H, L;
        H.u[0] = packpair(x.x, x.y); H.u[1] = packpair(x.z, x.w);
        H.u[2] = packpair(y.x, y.y); H.u[3] = packpair(y.z, y.w);
        L.u[0] = packpair(x.x - bftrunc(x.x), x.y - bftrunc(x.y));
        L.u[1] = packpair(x.z - bftrunc(x.z), x.w - bftrunc(x.w));
        L.u[2] = packpair(y.x - bftrunc(y.x), y.y - bftrunc(y.y));
        L.u[3] = packpair(y.z - bftrunc(y.z), y.w - bftrunc(y.w));
        afr[ks] = (lane & 8) ? L.s : H.s;
    }
    const float qbh = qb2[r * NH + (t & 7)];
    const float eqb = __builtin_amdgcn_exp2f(qbh);

    const int kk = t >> 3, dh = t & 7;

    float4 va[16];
    auto issue_loads = [&](int kt) {
        const int lev = kt >> 2;
        const int Wl = 1024 >> lev, Hl = 64 >> lev;
        const int lsi = (lev == 0) ? 0 : (lev == 1) ? 65536 : (lev == 2) ? 81920 : 86016;
        const int tcpx = (int)rintf(tcf * (float)Wl - 0.5f);
        const int fcpx = (int)rintf(fcf * (float)Hl - 0.5f);
        #pragma unroll
        for (int i = 0; i < 8; ++i) {
            const int kl = (kt & 3) * 32 + w * 8 + i;
            const int tt = tcpx + (kl & 15) - 8;
            const int ff = fcpx + (kl >> 4) - 4;
            const int row = lsi + min(max(ff, 0), Hl - 1) * Wl + min(max(tt, 0), Wl - 1);
            const float* sp = vb + (size_t)row * DIM + dl * 8;
            va[2 * i]     = *(const float4*)sp;
            va[2 * i + 1] = *(const float4*)(sp + 4);
        }
    };
    issue_loads(0);

    f32x4 acco[8];
    #pragma unroll
    for (int nt = 0; nt < 8; ++nt) acco[nt] = (f32x4){0.f, 0.f, 0.f, 0.f};
    float lsum = 0.f;

    #pragma unroll
    for (int kt = 0; kt < 16; ++kt) {
        #pragma unroll
        for (int i = 0; i < 8; ++i) {
            float4 v0 = va[2 * i], v1 = va[2 * i + 1];
            uint4 H;
            H.x = packpair(v0.x, v0.y); H.y = packpair(v0.z, v0.w);
            H.z = packpair(v1.x, v1.y); H.w = packpair(v1.z, v1.w);
            const int key = w * 8 + i;
            *(uint4*)(smem + tok_addr(key, dl * 16)) = H;
        }
        #pragma unroll
        for (int dd = 0; dd < 8; ++dd) {
            uint4 D;
            const int hi = dd >> 2, c = dd & 3;
            D.x = packpair(((const float*)&va[0 + hi])[c],  ((const float*)&va[2 + hi])[c]);
            D.y = packpair(((const float*)&va[4 + hi])[c],  ((const float*)&va[6 + hi])[c]);
            D.z = packpair(((const float*)&va[8 + hi])[c],  ((const float*)&va[10 + hi])[c]);
            D.w = packpair(((const float*)&va[12 + hi])[c], ((const float*)&va[14 + hi])[c]);
            const int d = dl * 8 + dd;
            *(uint4*)(smem + DIMP + d * 64 + ((w * 16) ^ ((dl & 3) << 4))) = D;
        }
        if (kt < 15) issue_loads(kt + 1);
        __syncthreads();

        f32x4 dacc[2];
        dacc[0] = (f32x4){0.f, 0.f, 0.f, 0.f};
        dacc[1] = (f32x4){0.f, 0.f, 0.f, 0.f};
        #pragma unroll
        for (int ks = 0; ks < 4; ++ks) {
            const int dby = w * 256 + ks * 64 + q * 16;
            #pragma unroll
            for (int ko = 0; ko < 2; ++ko) {
                const int key = m + 16 * ko;
                short8v bhi = *(const short8v*)(smem + tok_addr(key, dby));
                dacc[ko] = __builtin_amdgcn_mfma_f32_16x16x32_bf16(afr[ks], bhi, dacc[ko], 0, 0, 0);
            }
        }
        *(f32x4*)(smem + PARTB + w * 2048 + m * 64 + q * 16)        = dacc[0];
        *(f32x4*)(smem + PARTB + w * 2048 + (m + 16) * 64 + q * 16) = dacc[1];
        __syncthreads();

        {
            float s = 0.f;
            #pragma unroll
            for (int w4 = 0; w4 < 4; ++w4) {
                s += *(const float*)(smem + PARTB + w4 * 2048 + kk * 64 + dh * 4);
                s += *(const float*)(smem + PARTB + w4 * 2048 + kk * 64 + (dh + 8) * 4);
            }
            const int lev = kt >> 2;
            const int Wl = 1024 >> lev, Hl = 64 >> lev;
            const int tcpx = (int)rintf(tcf * (float)Wl - 0.5f);
            const int fcpx = (int)rintf(fcf * (float)Hl - 0.5f);
            const int kl = (kt & 3) * 32 + kk;
            const int tt = tcpx + (kl & 15) - 8;
            const int ff = fcpx + (kl >> 4) - 4;
            const bool oob = (tt < 0) | (tt >= Wl) | (ff < 0) | (ff >= Hl);
            const float p = __builtin_amdgcn_exp2f(s + qbh);
            lsum += oob ? eqb : p;
            unsigned short pb = 0;
            if (!oob) {
                const unsigned u = __float_as_uint(p);
                pb = (unsigned short)((u + 0x7FFFu + ((u >> 16) & 1u)) >> 16);
            }
            *(unsigned short*)(smem + PLDSB + dh * 64 + kk * 2) = pb;
        }
        __syncthreads();

        {
            short8v pa = *(const short8v*)(smem + PLDSB + m * 64 + q * 16);
            #pragma unroll
            for (int nt = 0; nt < 8; ++nt) {
                const int d = w * 128 + nt * 16 + m;
                short8v bv = *(const short8v*)(smem + DIMP + d * 64 +
                                               ((q * 16) ^ (((d >> 3) & 3) << 4)));
                acco[nt] = __builtin_amdgcn_mfma_f32_16x16x32_bf16(pa, bv, acco[nt], 0, 0, 0);
            }
        }
        __syncthreads();
    }

    if (q < 2) {
        float* tsr = ts + (size_t)r * 4096 + (q * 4) * 512 + w * 128 + m;
        #pragma unroll
        for (int nt = 0; nt < 8; ++nt)
            #pragma unroll
            for (int jj = 0; jj < 4; ++jj)
                tsr[jj * 512 + nt * 16] = acco[nt][jj];
    }
    lsum += __shfl_xor(lsum, 8);
    lsum += __shfl_xor(lsum, 16);
    lsum += __shfl_xor(lsum, 32);
    if (lane < 8) *(float*)(smem + PARTB + (w * 8 + lane) * 4) = lsum;
    __syncthreads();
    if (t < 8) {
        float a = 0.f;
        #pragma unroll
        for (int w4 = 0; w4 < 4; ++w4)
            a += *(const float*)(smem + PARTB + (w4 * 8 + t) * 4);
        lout[r * NH + t] = a;
    }
}

// ---------------------------------------------------------------------------
// Kernel 4a: o1 = (ts/l) @ Wv + bv, 16x64 tiles, grid(64, 8) = 512 blocks.
// ---------------------------------------------------------------------------
__global__ __launch_bounds__(256)
void k_gemm1(const float* __restrict__ ts, const float* __restrict__ lp,
             const float* __restrict__ Wv, const float* __restrict__ bv,
             float* __restrict__ o1) {
    __shared__ float As[32][17];
    __shared__ float Bs[32][68];
    const int rb = blockIdx.x, h = blockIdx.y, t = threadIdx.x;
    const int tx = t & 15, ty = t >> 4;
    float acc[4] = {0.f, 0.f, 0.f, 0.f};

    for (int kb = 0; kb < 16; ++kb) {
        {
            const int row = t >> 4, kq = t & 15;
            const float2 a0 = *(const float2*)(ts + (size_t)(rb * 16 + row) * 4096 + h * 512 + kb * 32 + kq * 2);
            As[kq * 2 + 0][row] = a0.x; As[kq * 2 + 1][row] = a0.y;
            const int kr = t >> 3, cq = t & 7;
            const float* bp = Wv + (size_t)(kb * 32 + kr) * 512 + h * 64 + cq * 8;
            *(float4*)&Bs[kr][cq * 8]     = ((const float4*)bp)[0];
            *(float4*)&Bs[kr][cq * 8 + 4] = ((const float4*)bp)[1];
        }
        __syncthreads();
        #pragma unroll 8
        for (int k = 0; k < 32; ++k) {
            const float av = As[k][ty];
            float4 bw = *(const float4*)&Bs[k][tx * 4];
            acc[0] = fmaf(av, bw.x, acc[0]); acc[1] = fmaf(av, bw.y, acc[1]);
            acc[2] = fmaf(av, bw.z, acc[2]); acc[3] = fmaf(av, bw.w, acc[3]);
        }
        __syncthreads();
    }
    const int r = rb * 16 + ty;
    const float inv = 1.f / lp[r * NH + h];
    #pragma unroll
    for (int j = 0; j < 4; ++j) {
        const int c = h * 64 + tx * 4 + j;
        o1[(size_t)r * 512 + c] = acc[j] * inv + bv[c];
    }
}

// ---------------------------------------------------------------------------
extern "C" void kernel_launch(void* const* d_in, const int* in_sizes, int n_in,
                              void* d_out, int out_size, void* d_ws, size_t ws_size,
                              hipStream_t stream) {
    const float* query = (const float*)d_in[0];
    const float* tc    = (const float*)d_in[1];
    const float* fc    = (const float*)d_in[2];
    const float* value = (const float*)d_in[3];
    const float* Wq    = (const float*)d_in[4];
    const float* bq    = (const float*)d_in[5];
    const float* Wk    = (const float*)d_in[6];
    const float* bk    = (const float*)d_in[7];
    const float* Wv    = (const float*)d_in[8];
    const float* bv    = (const float*)d_in[9];
    const float* Wo    = (const float*)d_in[10];
    const float* bo    = (const float*)d_in[11];
    float* out = (float*)d_out;

    char* ws = (char*)d_ws;
    float* Q   = (float*)(ws);                      //  2 MB
    float* QT2 = (float*)(ws + (size_t)(2  << 20)); // 16 MB
    float* QB2 = (float*)(ws + (size_t)(18 << 20)); // 32 KB
    float* TS  = (float*)(ws + (size_t)(19 << 20)); // 16 MB
    float* L   = (float*)(ws + (size_t)(35 << 20)); // 32 KB
    float* O1  = (float*)(ws + (size_t)(36 << 20)); //  2 MB

    hipLaunchKernelGGL(k_gemm2,  dim3(64, 8),    dim3(256), 0, stream, query, Wq, bq, Q);
    hipLaunchKernelGGL(k_qtilde, dim3(16, 8, 8), dim3(256), 0, stream, Q, Wk, bk, QT2, QB2);
    hipLaunchKernelGGL(k_attn,   dim3(1024),     dim3(256), 0, stream,
                       value, tc, fc, QT2, QB2, TS, L);
    hipLaunchKernelGGL(k_gemm1,  dim3(64, 8),    dim3(256), 0, stream, TS, L, Wv, bv, O1);
    hipLaunchKernelGGL(k_gemm2,  dim3(64, 8),    dim3(256), 0, stream, O1, Wo, bo, out);
}